// Round 1
// baseline (2610.184 us; speedup 1.0000x reference)
//
#include <hip/hip_runtime.h>
#include <hip/hip_bf16.h>
#include <stdint.h>

#define NROWS 100000
#define MPAD  100096      // 782 * 128
#define INDIM 3000
#define KPAD0 3072        // 48 * 64
#define HDIM  512
#define LATD  20

typedef unsigned short u16;
typedef __attribute__((ext_vector_type(8))) short bf16x8;
typedef __attribute__((ext_vector_type(4))) float f32x4;

// ws layout (bytes)
#define OFF_W0T 0
#define OFF_W1T (512 * 3072 * 2)
#define OFF_W2T (OFF_W1T + 512 * 512 * 2)
#define OFF_H1  (OFF_W2T + 512 * 512 * 2)
#define OFF_H2  (OFF_H1 + (size_t)MPAD * HDIM * 2)
#define WS_NEED (OFF_H2 + (size_t)MPAD * HDIM * 2)

__device__ __forceinline__ u16 f2bf(float f) {
    union { float f; unsigned u; } v; v.f = f;
    unsigned r = v.u + 0x7FFFu + ((v.u >> 16) & 1u);  // RTN-even
    return (u16)(r >> 16);
}
__device__ __forceinline__ float bf2f(u16 b) {
    union { unsigned u; float f; } v; v.u = ((unsigned)b) << 16;
    return v.f;
}

// async global->LDS, 16B per lane; lds ptr must be wave-uniform
#define GLDS16(gp, lp) __builtin_amdgcn_global_load_lds( \
    (const __attribute__((address_space(1))) unsigned int*)(gp), \
    (__attribute__((address_space(3))) unsigned int*)(lp), 16, 0, 0)

// ---------------- weight prep: cast + transpose to [N][K] bf16 ----------------
__global__ __launch_bounds__(256) void prep_weights(
    const float* __restrict__ W0, const float* __restrict__ W1,
    const float* __restrict__ W2, u16* __restrict__ w0t,
    u16* __restrict__ w1t, u16* __restrict__ w2t)
{
    int idx = blockIdx.x * 256 + threadIdx.x;
    if (idx < HDIM * KPAD0) {
        int n = idx / KPAD0, k = idx - n * KPAD0;
        float v = (k < INDIM) ? W0[(size_t)k * HDIM + n] : 0.0f;
        w0t[idx] = f2bf(v);
    } else {
        int i1 = idx - HDIM * KPAD0;
        if (i1 < HDIM * HDIM) {
            int n = i1 >> 9, k = i1 & 511;
            w1t[i1] = f2bf(W1[(size_t)k * HDIM + n]);
            w2t[i1] = f2bf(W2[(size_t)k * HDIM + n]);
        }
    }
}

// ---------------- layer 0: A fp32 (fused cast), Bt bf16 [512][3072] ----------------
__global__ __launch_bounds__(256) void gemm0(
    const float* __restrict__ X, const u16* __restrict__ Bt,
    const float* __restrict__ bias, u16* __restrict__ Cout)
{
    __shared__ u16 As[128 * 64];
    __shared__ u16 Bs[128 * 64];
    const int tid = threadIdx.x;
    const int wave = tid >> 6, lane = tid & 63;
    const int wm = (wave >> 1) << 6, wn = (wave & 1) << 6;
    const int m0 = blockIdx.y << 7, n0 = blockIdx.x << 7;
    const int quad = lane >> 4, l16 = lane & 15;

    f32x4 acc[4][4] = {};

    for (int k0 = 0; k0 < KPAD0; k0 += 64) {
        // B tile: async DMA (source pre-padded with zeros for k>=3000)
        #pragma unroll
        for (int i = 0; i < 4; ++i) {
            int c = (wave * 4 + i) * 64 + lane;
            int r = c >> 3, kc = (c & 7) << 3;
            GLDS16(Bt + (size_t)(n0 + r) * KPAD0 + k0 + kc, &Bs[(wave * 4 + i) * 512]);
        }
        // A tile: fp32 loads (coalesced 16B/lane), convert, ds_write
        float4 av[8];
        #pragma unroll
        for (int i = 0; i < 8; ++i) {
            int c = i * 256 + tid;
            int r = c >> 4, kc = (c & 15) << 2;
            int k = k0 + kc;
            int rg = m0 + r; rg = rg < NROWS ? rg : NROWS - 1;  // clamp: read valid mem, row discarded in epilogue
            if (k < INDIM) av[i] = *(const float4*)(X + (size_t)rg * INDIM + k);
            else           av[i] = make_float4(0.f, 0.f, 0.f, 0.f);
        }
        #pragma unroll
        for (int i = 0; i < 8; ++i) {
            int c = i * 256 + tid;
            int r = c >> 4, kc = (c & 15) << 2;
            ushort4 b;
            b.x = f2bf(av[i].x); b.y = f2bf(av[i].y);
            b.z = f2bf(av[i].z); b.w = f2bf(av[i].w);
            *(ushort4*)&As[r * 64 + kc] = b;
        }
        __syncthreads();
        #pragma unroll
        for (int ks = 0; ks < 2; ++ks) {
            bf16x8 af[4], bfr[4];
            #pragma unroll
            for (int mi = 0; mi < 4; ++mi)
                af[mi] = *(const bf16x8*)&As[(wm + mi * 16 + l16) * 64 + ks * 32 + quad * 8];
            #pragma unroll
            for (int ni = 0; ni < 4; ++ni)
                bfr[ni] = *(const bf16x8*)&Bs[(wn + ni * 16 + l16) * 64 + ks * 32 + quad * 8];
            #pragma unroll
            for (int mi = 0; mi < 4; ++mi)
                #pragma unroll
                for (int ni = 0; ni < 4; ++ni)
                    acc[mi][ni] = __builtin_amdgcn_mfma_f32_16x16x32_bf16(
                        af[mi], bfr[ni], acc[mi][ni], 0, 0, 0);
        }
        __syncthreads();
    }
    #pragma unroll
    for (int ni = 0; ni < 4; ++ni) {
        int col = n0 + wn + ni * 16 + l16;
        float bv = bias[col];
        #pragma unroll
        for (int mi = 0; mi < 4; ++mi) {
            #pragma unroll
            for (int rg = 0; rg < 4; ++rg) {
                int row = m0 + wm + mi * 16 + quad * 4 + rg;
                if (row < NROWS) {
                    float v = acc[mi][ni][rg] + bv;
                    Cout[(size_t)row * HDIM + col] = f2bf(v > 0.f ? v : 0.f);
                }
            }
        }
    }
}

// ---------------- layers 1,2: bf16 A [MPAD][512], Bt bf16 [512][512] ----------------
__global__ __launch_bounds__(256) void gemm_bt(
    const u16* __restrict__ A, const u16* __restrict__ Bt,
    const float* __restrict__ bias, u16* __restrict__ Cout)
{
    __shared__ u16 As[128 * 64];
    __shared__ u16 Bs[128 * 64];
    const int tid = threadIdx.x;
    const int wave = tid >> 6, lane = tid & 63;
    const int wm = (wave >> 1) << 6, wn = (wave & 1) << 6;
    const int m0 = blockIdx.y << 7, n0 = blockIdx.x << 7;
    const int quad = lane >> 4, l16 = lane & 15;

    f32x4 acc[4][4] = {};

    for (int k0 = 0; k0 < HDIM; k0 += 64) {
        #pragma unroll
        for (int i = 0; i < 4; ++i) {
            int c = (wave * 4 + i) * 64 + lane;
            int r = c >> 3, kc = (c & 7) << 3;
            GLDS16(A  + (size_t)(m0 + r) * HDIM + k0 + kc, &As[(wave * 4 + i) * 512]);
            GLDS16(Bt + (size_t)(n0 + r) * HDIM + k0 + kc, &Bs[(wave * 4 + i) * 512]);
        }
        __syncthreads();
        #pragma unroll
        for (int ks = 0; ks < 2; ++ks) {
            bf16x8 af[4], bfr[4];
            #pragma unroll
            for (int mi = 0; mi < 4; ++mi)
                af[mi] = *(const bf16x8*)&As[(wm + mi * 16 + l16) * 64 + ks * 32 + quad * 8];
            #pragma unroll
            for (int ni = 0; ni < 4; ++ni)
                bfr[ni] = *(const bf16x8*)&Bs[(wn + ni * 16 + l16) * 64 + ks * 32 + quad * 8];
            #pragma unroll
            for (int mi = 0; mi < 4; ++mi)
                #pragma unroll
                for (int ni = 0; ni < 4; ++ni)
                    acc[mi][ni] = __builtin_amdgcn_mfma_f32_16x16x32_bf16(
                        af[mi], bfr[ni], acc[mi][ni], 0, 0, 0);
        }
        __syncthreads();
    }
    #pragma unroll
    for (int ni = 0; ni < 4; ++ni) {
        int col = n0 + wn + ni * 16 + l16;
        float bv = bias[col];
        #pragma unroll
        for (int mi = 0; mi < 4; ++mi) {
            #pragma unroll
            for (int rg = 0; rg < 4; ++rg) {
                int row = m0 + wm + mi * 16 + quad * 4 + rg;
                if (row < NROWS) {
                    float v = acc[mi][ni][rg] + bv;
                    Cout[(size_t)row * HDIM + col] = f2bf(v > 0.f ? v : 0.f);
                }
            }
        }
    }
}

// ---------------- layer 3: [100000,512] @ [512,20] + b, relu, fp32 out ----------------
__global__ __launch_bounds__(256) void layer3(
    const u16* __restrict__ H, const float* __restrict__ W3,
    const float* __restrict__ b3, float* __restrict__ Out)
{
    __shared__ float Wt[LATD][513];  // transposed + padded: conflict-free (bank = (j+l)%32)
    for (int i = threadIdx.x; i < HDIM * LATD; i += 256) {
        int k = i / LATD, j = i - k * LATD;
        Wt[j][k] = W3[i];
    }
    __syncthreads();

    const int wave = threadIdx.x >> 6, lane = threadIdx.x & 63;
    const int wg = blockIdx.x * 4 + wave;
    const int nw = gridDim.x * 4;

    for (int row = wg; row < NROWS; row += nw) {
        const u16* rp = H + (size_t)row * HDIM;
        float x[8];
        #pragma unroll
        for (int i = 0; i < 8; ++i) x[i] = bf2f(rp[i * 64 + lane]);

        float accv[LATD];
        #pragma unroll
        for (int j = 0; j < LATD; ++j) accv[j] = 0.f;
        #pragma unroll
        for (int i = 0; i < 8; ++i)
            #pragma unroll
            for (int j = 0; j < LATD; ++j)
                accv[j] += x[i] * Wt[j][i * 64 + lane];

        #pragma unroll
        for (int j = 0; j < LATD; ++j) {
            float s = accv[j];
            s += __shfl_down(s, 32);
            s += __shfl_down(s, 16);
            s += __shfl_down(s, 8);
            s += __shfl_down(s, 4);
            s += __shfl_down(s, 2);
            s += __shfl_down(s, 1);
            accv[j] = s;
        }
        if (lane == 0) {
            float r[LATD];
            #pragma unroll
            for (int j = 0; j < LATD; ++j) {
                float v = accv[j] + b3[j];
                r[j] = v > 0.f ? v : 0.f;
            }
            float4* op = (float4*)(Out + (size_t)row * LATD);
            op[0] = make_float4(r[0],  r[1],  r[2],  r[3]);
            op[1] = make_float4(r[4],  r[5],  r[6],  r[7]);
            op[2] = make_float4(r[8],  r[9],  r[10], r[11]);
            op[3] = make_float4(r[12], r[13], r[14], r[15]);
            op[4] = make_float4(r[16], r[17], r[18], r[19]);
        }
    }
}

extern "C" void kernel_launch(void* const* d_in, const int* in_sizes, int n_in,
                              void* d_out, int out_size, void* d_ws, size_t ws_size,
                              hipStream_t stream) {
    const float* X  = (const float*)d_in[0];
    // d_in[1] = g (dead)
    const float* W0 = (const float*)d_in[2];
    const float* b0 = (const float*)d_in[3];
    const float* W1 = (const float*)d_in[4];
    const float* b1 = (const float*)d_in[5];
    const float* W2 = (const float*)d_in[6];
    const float* b2 = (const float*)d_in[7];
    const float* W3 = (const float*)d_in[8];
    const float* b3 = (const float*)d_in[9];
    float* out = (float*)d_out;

    if (ws_size < WS_NEED) return;  // insufficient scratch: bail (output stays wrong but no OOB)

    char* ws = (char*)d_ws;
    u16* w0t = (u16*)(ws + OFF_W0T);
    u16* w1t = (u16*)(ws + OFF_W1T);
    u16* w2t = (u16*)(ws + OFF_W2T);
    u16* h1  = (u16*)(ws + OFF_H1);
    u16* h2  = (u16*)(ws + OFF_H2);

    hipLaunchKernelGGL(prep_weights, dim3(7168), dim3(256), 0, stream, W0, W1, W2, w0t, w1t, w2t);
    hipLaunchKernelGGL(gemm0,   dim3(4, 782), dim3(256), 0, stream, X,  w0t, b0, h1);
    hipLaunchKernelGGL(gemm_bt, dim3(4, 782), dim3(256), 0, stream, h1, w1t, b1, h2);
    hipLaunchKernelGGL(gemm_bt, dim3(4, 782), dim3(256), 0, stream, h2, w2t, b2, h1);  // h3 reuses h1
    hipLaunchKernelGGL(layer3,  dim3(1024),   dim3(256), 0, stream, h1, W3, b3, out);
}